// Round 4
// baseline (616.945 us; speedup 1.0000x reference)
//
#include <hip/hip_runtime.h>
#include <hip/hip_bf16.h>
#include <stdint.h>

#define BDIM 512
#define CDIM 200000
#define DDIM 256
#define S_SC 30.0f
#define MARG 0.2f
#define LOG2E_S 43.2808512f   // 30 * log2(e): exp(30x) = exp2(x * 43.28...)

#define BN 128
#define NBLK 1563      // ceil(200000/128); 64 zero-padded classes in last block
#define NPAD 64.0f     // padded classes contribute exp(0)=1 each -> subtract

typedef float f4 __attribute__((ext_vector_type(4)));
typedef float f32x4 __attribute__((ext_vector_type(4)));
typedef short bf16x8 __attribute__((ext_vector_type(8)));
typedef unsigned short u16x4 __attribute__((ext_vector_type(4)));

__device__ __forceinline__ unsigned short f2bf(float f) {
  unsigned int u = __float_as_uint(f);
  u += 0x7FFF + ((u >> 16) & 1);   // RNE
  return (unsigned short)(u >> 16);
}

__device__ __forceinline__ float wave_allsum(float v) {
#pragma unroll
  for (int off = 32; off >= 1; off >>= 1) v += __shfl_xor(v, off);
  return v;
}

// ---- kernel 1: normalize x, emit MFMA-B-fragment-ordered bf16 buffer ----
// xn_frag layout (bt, kk, lane): 8 bf16 = xn[bt*16 + (lane&15)][kk*32 + (lane>>4)*8 + j]
__global__ __launch_bounds__(512) void k_xfrag(const float* __restrict__ x,
                                               unsigned short* __restrict__ xn_frag) {
  __shared__ float xtile[16][260];
  __shared__ float sscale[16];
  const int tid = threadIdx.x;
  const int lane = tid & 63;
  const int wv = tid >> 6;
  const int bt = blockIdx.x;         // 32 blocks, 16 batch rows each

  #pragma unroll
  for (int h = 0; h < 2; ++h) {
    const int r = wv * 2 + h;
    f4 v = *(const f4*)(x + (size_t)(bt * 16 + r) * DDIM + lane * 4);
    float ssq = v[0]*v[0] + v[1]*v[1] + v[2]*v[2] + v[3]*v[3];
    ssq = wave_allsum(ssq);
    if (lane == 0) sscale[r] = 1.0f / fmaxf(sqrtf(ssq), 1e-12f);
    *(f4*)&xtile[r][lane * 4] = v;
  }
  __syncthreads();

  const int kk = wv;
  const int r = lane & 15;
  const int c0f = kk * 32 + (lane >> 4) * 8;
  const float sc = sscale[r];
  f4 a = *(const f4*)&xtile[r][c0f];
  f4 b = *(const f4*)&xtile[r][c0f + 4];
  bf16x8 o;
  o[0] = (short)f2bf(a[0]*sc); o[1] = (short)f2bf(a[1]*sc);
  o[2] = (short)f2bf(a[2]*sc); o[3] = (short)f2bf(a[3]*sc);
  o[4] = (short)f2bf(b[0]*sc); o[5] = (short)f2bf(b[1]*sc);
  o[6] = (short)f2bf(b[2]*sc); o[7] = (short)f2bf(b[3]*sc);
  *(bf16x8*)(xn_frag + ((size_t)(bt * 8 + kk) * 64 + lane) * 8) = o;
}

// ---- kernel 2: fused normalize(w) + bf16 MFMA + exp2-sum over 128 classes ----
// (512,3): ~170-VGPR budget so the scheduler can pipeline ds_reads across the
// fully-unrolled cf loop (R3 was stall-bound: MfmaUtil 17.7% with no pipe >43%).
__global__ __launch_bounds__(512, 3) void k_gemm(const float* __restrict__ w,
                                                 const unsigned short* __restrict__ xn_frag,
                                                 float* __restrict__ partial) {
  __shared__ char wb[BN * 512];      // 128 class rows x 512B bf16, XOR-swizzled
  const int tid = threadIdx.x;
  const int lane = tid & 63;
  const int wv = tid >> 6;           // 8 waves
  const int c0 = blockIdx.x * BN;

  // ---- stage: 16 w-rows per wave; loads hoisted, butterflies interleaved ----
  f4 v[16];
  #pragma unroll
  for (int rr = 0; rr < 16; ++rr) {
    const int cg = c0 + wv * 16 + rr;
    f4 z = {0.f, 0.f, 0.f, 0.f};
    v[rr] = (cg < CDIM) ? *(const f4*)(w + (size_t)cg * DDIM + lane * 4) : z;
  }
  float ss[16];
  #pragma unroll
  for (int rr = 0; rr < 16; ++rr)
    ss[rr] = v[rr][0]*v[rr][0] + v[rr][1]*v[rr][1] + v[rr][2]*v[rr][2] + v[rr][3]*v[rr][3];
  #pragma unroll
  for (int off = 32; off >= 1; off >>= 1) {
    #pragma unroll
    for (int rr = 0; rr < 16; ++rr) ss[rr] += __shfl_xor(ss[rr], off);
  }
  #pragma unroll
  for (int rr = 0; rr < 16; ++rr) {
    const int row = wv * 16 + rr;
    const float sc = 1.0f / fmaxf(sqrtf(ss[rr]), 1e-12f);  // zero pad-row -> stays 0
    u16x4 o;
    o[0] = f2bf(v[rr][0]*sc); o[1] = f2bf(v[rr][1]*sc);
    o[2] = f2bf(v[rr][2]*sc); o[3] = f2bf(v[rr][3]*sc);
    const int byte = (row * 512 + lane * 8) ^ ((row & 7) << 4);
    *(u16x4*)(wb + byte) = o;
  }
  __syncthreads();

  // ---- main: 2 passes x 2 batch-tiles in regs; stream 128 classes from LDS ----
  #pragma unroll 1
  for (int o2 = 0; o2 < 2; ++o2) {
    bf16x8 bf[2][8];
    #pragma unroll
    for (int bt2 = 0; bt2 < 2; ++bt2) {
      const int bt = wv * 4 + o2 * 2 + bt2;
      #pragma unroll
      for (int kkk = 0; kkk < 8; ++kkk)
        bf[bt2][kkk] = *(const bf16x8*)(xn_frag + ((size_t)(bt * 8 + kkk) * 64 + lane) * 8);
    }
    float e0 = 0.f, e1 = 0.f;
    #pragma unroll    // full unroll: one straight-line region, scheduler pipelines
    for (int cf = 0; cf < 8; ++cf) {
      bf16x8 af[8];
      const int arow = cf * 16 + (lane & 15);
      const int asw = (arow & 7) << 4;
      #pragma unroll
      for (int kkk = 0; kkk < 8; ++kkk) {
        const int byte = (arow * 512 + kkk * 64 + (lane >> 4) * 16) ^ asw;
        af[kkk] = *(const bf16x8*)(wb + byte);
      }
      f32x4 a0 = {0.f,0.f,0.f,0.f}, a1 = {0.f,0.f,0.f,0.f};
      #pragma unroll
      for (int kkk = 0; kkk < 8; ++kkk) {
        a0 = __builtin_amdgcn_mfma_f32_16x16x32_bf16(af[kkk], bf[0][kkk], a0, 0, 0, 0);
        a1 = __builtin_amdgcn_mfma_f32_16x16x32_bf16(af[kkk], bf[1][kkk], a1, 0, 0, 0);
      }
      // no pad-guard: padded classes give exp2(0)=1, subtracted once in k_row
      #pragma unroll
      for (int q = 0; q < 4; ++q) {
        e0 += exp2f(a0[q] * LOG2E_S);
        e1 += exp2f(a1[q] * LOG2E_S);
      }
    }
    e0 += __shfl_xor(e0, 16); e0 += __shfl_xor(e0, 32);
    e1 += __shfl_xor(e1, 16); e1 += __shfl_xor(e1, 32);
    const int bt0 = wv * 4 + o2 * 2;
    if (lane < 16) {   // [blk][row] layout: 64B-line-aligned stores, minimal WB
      partial[(size_t)blockIdx.x * BDIM + bt0 * 16 + lane] = e0;
      partial[(size_t)blockIdx.x * BDIM + (bt0 + 1) * 16 + lane] = e1;
    }
  }
}

// ---- kernel 3: per-row reduce + fp32 target cosine + NLL ----
__global__ __launch_bounds__(256) void k_row(const float* __restrict__ partial,
                                             const float* __restrict__ x,
                                             const float* __restrict__ w,
                                             const int* __restrict__ tg,
                                             float* __restrict__ nll) {
  const int b = blockIdx.x;
  const int tid = threadIdx.x;
  const int lane = tid & 63;
  const int wv = tid >> 6;
  __shared__ float s4[4];
  __shared__ float sct;

  // strided column reads; 3.2 MB total data stays L2/L3-resident
  float s = 0.f;
  for (int r = tid; r < NBLK; r += 256) s += partial[(size_t)r * BDIM + b];
  s = wave_allsum(s);
  if (lane == 0) s4[wv] = s;

  if (wv == 0) {   // fp32 target cosine
    const int t = tg[b];
    f4 xv = *(const f4*)(x + (size_t)b * DDIM + lane * 4);
    f4 wv4 = *(const f4*)(w + (size_t)t * DDIM + lane * 4);
    float sx = xv[0]*xv[0] + xv[1]*xv[1] + xv[2]*xv[2] + xv[3]*xv[3];
    float sw = wv4[0]*wv4[0] + wv4[1]*wv4[1] + wv4[2]*wv4[2] + wv4[3]*wv4[3];
    float sd = xv[0]*wv4[0] + xv[1]*wv4[1] + xv[2]*wv4[2] + xv[3]*wv4[3];
    sx = wave_allsum(sx);
    sw = wave_allsum(sw);
    sd = wave_allsum(sd);
    if (lane == 0)
      sct = sd / (fmaxf(sqrtf(sx), 1e-12f) * fmaxf(sqrtf(sw), 1e-12f));
  }
  __syncthreads();

  if (tid == 0) {
    const float sumexp = s4[0] + s4[1] + s4[2] + s4[3] - NPAD;  // remove pad classes
    const float ct = sct;
    const float tl = S_SC * (ct - MARG);
    const float adj = sumexp - __expf(S_SC * ct) + __expf(tl);
    nll[b] = logf(adj) - tl;
  }
}

// ---- kernel 4: mean over 512 rows ----
__global__ __launch_bounds__(512) void k_final(const float* __restrict__ nll,
                                               float* __restrict__ out) {
  const int tid = threadIdx.x;
  float v = nll[tid];
  v = wave_allsum(v);
  __shared__ float s8[8];
  if ((tid & 63) == 0) s8[tid >> 6] = v;
  __syncthreads();
  if (tid == 0) {
    float t = 0.f;
    #pragma unroll
    for (int i = 0; i < 8; ++i) t += s8[i];
    out[0] = t / (float)BDIM;
  }
}

extern "C" void kernel_launch(void* const* d_in, const int* in_sizes, int n_in,
                              void* d_out, int out_size, void* d_ws, size_t ws_size,
                              hipStream_t stream) {
  const float* x = (const float*)d_in[0];       // 512*256 fp32
  const float* w = (const float*)d_in[1];       // 200000*256 fp32
  const int* tg = (const int*)d_in[2];          // 512 int

  char* ws = (char*)d_ws;
  unsigned short* xn_frag = (unsigned short*)ws;                     // 256 KiB
  float* partial = (float*)(ws + 262144);                            // 1563*512*4 B
  float* nll = (float*)(ws + 262144 + (size_t)NBLK * BDIM * 4);      // 2 KiB

  k_xfrag<<<32, 512, 0, stream>>>(x, xn_frag);
  k_gemm<<<NBLK, 512, 0, stream>>>(w, xn_frag, partial);
  k_row<<<BDIM, 256, 0, stream>>>(partial, x, w, tg, nll);
  k_final<<<1, 512, 0, stream>>>(nll, (float*)d_out);
}

// Round 6
// 339.611 us; speedup vs baseline: 1.8166x; 1.8166x over previous
//
#include <hip/hip_runtime.h>
#include <hip/hip_bf16.h>
#include <stdint.h>

#define BDIM 512
#define CDIM 200000
#define DDIM 256
#define S_SC 30.0f
#define MARG 0.2f
#define LOG2E_S 43.2808512f   // 30 * log2(e)

#define BN 64
#define NBLK 3125      // 200000/64 exactly — no padded classes

typedef float f4 __attribute__((ext_vector_type(4)));
typedef float f32x4 __attribute__((ext_vector_type(4)));
typedef short bf16x8 __attribute__((ext_vector_type(8)));
typedef unsigned short u16x4 __attribute__((ext_vector_type(4)));

__device__ __forceinline__ unsigned short f2bf(float f) {
  unsigned int u = __float_as_uint(f);
  u += 0x7FFF + ((u >> 16) & 1);   // RNE
  return (unsigned short)(u >> 16);
}

__device__ __forceinline__ float wave_allsum(float v) {
#pragma unroll
  for (int off = 32; off >= 1; off >>= 1) v += __shfl_xor(v, off);
  return v;
}

// ---- kernel 1: normalize x, emit MFMA-B-fragment-ordered bf16 buffer ----
// xn_frag (bt, kk, lane): 8 bf16 = xn[bt*16 + (lane&15)][kk*32 + (lane>>4)*8 + j]
__global__ __launch_bounds__(512) void k_xfrag(const float* __restrict__ x,
                                               unsigned short* __restrict__ xn_frag) {
  __shared__ float xtile[16][260];
  __shared__ float sscale[16];
  const int tid = threadIdx.x;
  const int lane = tid & 63;
  const int wv = tid >> 6;
  const int bt = blockIdx.x;         // 32 blocks, 16 batch rows each

  #pragma unroll
  for (int h = 0; h < 2; ++h) {
    const int r = wv * 2 + h;
    f4 v = *(const f4*)(x + (size_t)(bt * 16 + r) * DDIM + lane * 4);
    float ssq = v[0]*v[0] + v[1]*v[1] + v[2]*v[2] + v[3]*v[3];
    ssq = wave_allsum(ssq);
    if (lane == 0) sscale[r] = 1.0f / fmaxf(sqrtf(ssq), 1e-12f);
    *(f4*)&xtile[r][lane * 4] = v;
  }
  __syncthreads();

  const int kk = wv;
  const int r = lane & 15;
  const int c0f = kk * 32 + (lane >> 4) * 8;
  const float sc = sscale[r];
  f4 a = *(const f4*)&xtile[r][c0f];
  f4 b = *(const f4*)&xtile[r][c0f + 4];
  bf16x8 o;
  o[0] = (short)f2bf(a[0]*sc); o[1] = (short)f2bf(a[1]*sc);
  o[2] = (short)f2bf(a[2]*sc); o[3] = (short)f2bf(a[3]*sc);
  o[4] = (short)f2bf(b[0]*sc); o[5] = (short)f2bf(b[1]*sc);
  o[6] = (short)f2bf(b[2]*sc); o[7] = (short)f2bf(b[3]*sc);
  *(bf16x8*)(xn_frag + ((size_t)(bt * 8 + kk) * 64 + lane) * 8) = o;
}

// ---- kernel 2: raw-bf16(w) stage + MFMA + per-class norm at epilogue ----
// cosine = (bf16(w) . xn) * rsqrt(|w|^2): normalization deferred out of the
// stage chain. BN=64 -> 32KB LDS -> 4 blocks/CU; cf loop unroll 1 (R4 lesson).
__global__ __launch_bounds__(512, 4) void k_gemm(const float* __restrict__ w,
                                                 const unsigned short* __restrict__ xn_frag,
                                                 float* __restrict__ partial) {
  __shared__ char wb[BN * 512];      // 64 class rows x 512B bf16, XOR-swizzled
  __shared__ float ssqinv[BN];       // 43.28 * rsqrt(|w_row|^2)
  const int tid = threadIdx.x;
  const int lane = tid & 63;
  const int wv = tid >> 6;           // 8 waves
  const int c0 = blockIdx.x * BN;

  // ---- stage: 8 raw w-rows per wave (cast-only; ssq butterfly on the side) ----
  #pragma unroll
  for (int rr = 0; rr < 8; ++rr) {
    const int row = wv * 8 + rr;
    f4 v = *(const f4*)(w + (size_t)(c0 + row) * DDIM + lane * 4);
    u16x4 o;
    o[0] = f2bf(v[0]); o[1] = f2bf(v[1]); o[2] = f2bf(v[2]); o[3] = f2bf(v[3]);
    const int byte = (row * 512 + lane * 8) ^ ((row & 7) << 4);  // T2 swizzle
    *(u16x4*)(wb + byte) = o;
    float ss = v[0]*v[0] + v[1]*v[1] + v[2]*v[2] + v[3]*v[3];
    ss = wave_allsum(ss);
    if (lane == 0) ssqinv[row] = LOG2E_S * rsqrtf(fmaxf(ss, 1e-30f));
  }
  __syncthreads();

  // ---- main: 2 passes x 2 batch-tiles in regs; stream 64 classes from LDS ----
  #pragma unroll 1
  for (int o2 = 0; o2 < 2; ++o2) {
    const int btA = wv * 4 + o2 * 2;
    bf16x8 bf0[8], bf1[8];
    #pragma unroll
    for (int k = 0; k < 8; ++k) {
      bf0[k] = *(const bf16x8*)(xn_frag + ((size_t)(btA * 8 + k) * 64 + lane) * 8);
      bf1[k] = *(const bf16x8*)(xn_frag + ((size_t)((btA + 1) * 8 + k) * 64 + lane) * 8);
    }
    float e0 = 0.f, e1 = 0.f;
    #pragma unroll 1               // DO NOT fully unroll (R4: spills -> 3.5x regression)
    for (int cf = 0; cf < 4; ++cf) {
      bf16x8 af[8];
      const int arow = cf * 16 + (lane & 15);
      const int asw = (arow & 7) << 4;
      #pragma unroll
      for (int k = 0; k < 8; ++k) {
        const int byte = (arow * 512 + k * 64 + (lane >> 4) * 16) ^ asw;
        af[k] = *(const bf16x8*)(wb + byte);   // ds_read_b128, <=2-way
      }
      // per-class 43.28/|w| for this lane's 4 class rows
      f4 si = *(const f4*)((const char*)ssqinv + cf * 64 + (lane >> 4) * 16);
      f32x4 a0 = {0.f,0.f,0.f,0.f}, a1 = {0.f,0.f,0.f,0.f};
      __builtin_amdgcn_s_setprio(1);
      #pragma unroll
      for (int k = 0; k < 8; ++k) {
        a0 = __builtin_amdgcn_mfma_f32_16x16x32_bf16(af[k], bf0[k], a0, 0, 0, 0);
        a1 = __builtin_amdgcn_mfma_f32_16x16x32_bf16(af[k], bf1[k], a1, 0, 0, 0);
      }
      __builtin_amdgcn_s_setprio(0);
      // D: col(batch)=lane&15, row(class)=(lane>>4)*4+q; no pad classes
      #pragma unroll
      for (int q = 0; q < 4; ++q) {
        e0 += exp2f(a0[q] * si[q]);
        e1 += exp2f(a1[q] * si[q]);
      }
    }
    e0 += __shfl_xor(e0, 16); e0 += __shfl_xor(e0, 32);
    e1 += __shfl_xor(e1, 16); e1 += __shfl_xor(e1, 32);
    if (lane < 16) {   // [blk][row]: 64B-aligned coalesced stores
      partial[(size_t)blockIdx.x * BDIM + btA * 16 + lane] = e0;
      partial[(size_t)blockIdx.x * BDIM + (btA + 1) * 16 + lane] = e1;
    }
  }
}

// ---- kernel 3: per-row reduce + fp32 target cosine + NLL ----
__global__ __launch_bounds__(256) void k_row(const float* __restrict__ partial,
                                             const float* __restrict__ x,
                                             const float* __restrict__ w,
                                             const int* __restrict__ tg,
                                             float* __restrict__ nll) {
  const int b = blockIdx.x;
  const int tid = threadIdx.x;
  const int lane = tid & 63;
  const int wv = tid >> 6;
  __shared__ float s4[4];
  __shared__ float sct;

  float s = 0.f;
  for (int r = tid; r < NBLK; r += 256) s += partial[(size_t)r * BDIM + b];
  s = wave_allsum(s);
  if (lane == 0) s4[wv] = s;

  if (wv == 0) {   // fp32 target cosine
    const int t = tg[b];
    f4 xv = *(const f4*)(x + (size_t)b * DDIM + lane * 4);
    f4 wv4 = *(const f4*)(w + (size_t)t * DDIM + lane * 4);
    float sx = xv[0]*xv[0] + xv[1]*xv[1] + xv[2]*xv[2] + xv[3]*xv[3];
    float sw = wv4[0]*wv4[0] + wv4[1]*wv4[1] + wv4[2]*wv4[2] + wv4[3]*wv4[3];
    float sd = xv[0]*wv4[0] + xv[1]*wv4[1] + xv[2]*wv4[2] + xv[3]*wv4[3];
    sx = wave_allsum(sx);
    sw = wave_allsum(sw);
    sd = wave_allsum(sd);
    if (lane == 0)
      sct = sd / (fmaxf(sqrtf(sx), 1e-12f) * fmaxf(sqrtf(sw), 1e-12f));
  }
  __syncthreads();

  if (tid == 0) {
    const float sumexp = s4[0] + s4[1] + s4[2] + s4[3];
    const float ct = sct;
    const float tl = S_SC * (ct - MARG);
    const float adj = sumexp - __expf(S_SC * ct) + __expf(tl);
    nll[b] = logf(adj) - tl;
  }
}

// ---- kernel 4: mean over 512 rows ----
__global__ __launch_bounds__(512) void k_final(const float* __restrict__ nll,
                                               float* __restrict__ out) {
  const int tid = threadIdx.x;
  float v = nll[tid];
  v = wave_allsum(v);
  __shared__ float s8[8];
  if ((tid & 63) == 0) s8[tid >> 6] = v;
  __syncthreads();
  if (tid == 0) {
    float t = 0.f;
    #pragma unroll
    for (int i = 0; i < 8; ++i) t += s8[i];
    out[0] = t / (float)BDIM;
  }
}

extern "C" void kernel_launch(void* const* d_in, const int* in_sizes, int n_in,
                              void* d_out, int out_size, void* d_ws, size_t ws_size,
                              hipStream_t stream) {
  const float* x = (const float*)d_in[0];       // 512*256 fp32
  const float* w = (const float*)d_in[1];       // 200000*256 fp32
  const int* tg = (const int*)d_in[2];          // 512 int

  char* ws = (char*)d_ws;
  unsigned short* xn_frag = (unsigned short*)ws;                     // 256 KiB
  float* partial = (float*)(ws + 262144);                            // 3125*512*4 B
  float* nll = (float*)(ws + 262144 + (size_t)NBLK * BDIM * 4);      // 2 KiB

  k_xfrag<<<32, 512, 0, stream>>>(x, xn_frag);
  k_gemm<<<NBLK, 512, 0, stream>>>(w, xn_frag, partial);
  k_row<<<BDIM, 256, 0, stream>>>(partial, x, w, tg, nll);
  k_final<<<1, 512, 0, stream>>>(nll, (float*)d_out);
}